// Round 1
// baseline (2108.953 us; speedup 1.0000x reference)
//
#include <hip/hip_runtime.h>
#include <math.h>

#define NEG_INF (-3.402823466e+38f)

// ---- dims ----
constexpr int BATCH = 64, TQ = 40, TW = 12, TR = 4;
constexpr int NTOK = 4608;              // 2560 Q + 768 Wp + 256 Rp + 768 Wr + 256 Rr
constexpr int BH = 64 * 256;            // 16384, one (b,u) plane

// ---- ws offsets (floats) ----
constexpr size_t OFF_WIHT = 0;                          // 300*2048
constexpr size_t OFF_WQ   = OFF_WIHT + 300*2048;        // 2*64*4*256*4 = 524288
constexpr size_t OFF_L2T  = OFF_WQ   + 524288;          // 512*512
constexpr size_t OFF_B2   = OFF_L2T  + 262144;          // 2048
constexpr size_t OFF_XALL = OFF_B2   + 2048;            // 4608*300
constexpr size_t OFF_XP   = OFF_XALL + 1382400;         // 4608*2048
constexpr size_t OFF_HSQ  = OFF_XP   + 9437184;         // 2*40*BH
constexpr size_t OFF_HSWP = OFF_HSQ  + 2*40*BH;         // 2*12*BH
constexpr size_t OFF_HSRP = OFF_HSWP + 2*12*BH;         // 2*4*BH
constexpr size_t OFF_HSWR = OFF_HSRP + 2*4*BH;          // 2*12*BH
constexpr size_t OFF_HSRR = OFF_HSWR + 2*12*BH;         // 2*4*BH
constexpr size_t OFF_CS   = OFF_HSRR + 2*4*BH;          // 10*BH
constexpr size_t OFF_QO1  = OFF_CS   + 10*BH;           // 64*40*512
constexpr size_t OFF_RELP = OFF_QO1  + 1310720;         // 64*16*512
constexpr size_t OFF_RELC = OFF_RELP + 524288;
constexpr size_t OFF_RELW = OFF_RELC + 524288;
constexpr size_t OFF_EN   = OFF_RELW + 524288;          // 64*640
constexpr size_t OFF_ATT  = OFF_EN   + 40960;           // 64*40*512
constexpr size_t OFF_HM   = OFF_ATT  + 1310720;         // 64*150
// D, QO2, MT alias the XP region (XP dead after last lstm step)

// ================= prep: weight transposes =================
__global__ __launch_bounds__(256) void k_prep(
    const float* __restrict__ Wih_f, const float* __restrict__ Wih_b,
    const float* __restrict__ Whh_f, const float* __restrict__ Whh_b,
    const float* __restrict__ b_f,   const float* __restrict__ b_b,
    const float* __restrict__ l2w,
    float* __restrict__ WIHT, float* __restrict__ WQ,
    float* __restrict__ L2T,  float* __restrict__ B2) {
  int idx = blockIdx.x * 256 + threadIdx.x;
  if (idx < 614400) {                       // WIHT[k][n], n = dir*1024 + j
    int n = idx & 2047, k = idx >> 11;
    WIHT[idx] = (n < 1024) ? Wih_f[(size_t)n*300 + k]
                           : Wih_b[(size_t)(n-1024)*300 + k];
    return;
  }
  idx -= 614400;
  if (idx < 524288) {                       // WQ[d][k4][g][u][kk] = Whh_d[g*256+u][k4*4+kk]
    int d = idx >> 18, l = idx & 262143;
    int kk = l & 3, u = (l >> 2) & 255, g = (l >> 10) & 3, k4 = l >> 12;
    const float* Wh = d ? Whh_b : Whh_f;
    WQ[idx] = Wh[(size_t)(g*256 + u)*256 + k4*4 + kk];
    return;
  }
  idx -= 524288;
  if (idx < 262144) {                       // L2T[k][h] = l2w[h][k]
    int h = idx & 511, k = idx >> 9;
    L2T[idx] = l2w[(size_t)h*512 + k];
    return;
  }
  idx -= 262144;
  if (idx < 2048) B2[idx] = (idx < 1024) ? b_f[idx] : b_b[idx-1024];
}

// ================= gather embeddings =================
__global__ __launch_bounds__(320) void k_gather(
    const int* __restrict__ q,  const int* __restrict__ wr, const int* __restrict__ rr,
    const int* __restrict__ wp, const int* __restrict__ rp,
    const float* __restrict__ we, const float* __restrict__ re,
    float* __restrict__ XALL) {
  int m = blockIdx.x, k = threadIdx.x;
  if (k >= 300) return;
  const float* emb; int row;
  if (m < 2560)      { int t=m>>6,    b=m&63; row = q [b*40+t]; emb = we; }
  else if (m < 3328) { int mm=m-2560; int t=mm>>6,b=mm&63; row = wp[b*12+t]; emb = we; }
  else if (m < 3584) { int mm=m-3328; int t=mm>>6,b=mm&63; row = rp[b*4 +t]; emb = re; }
  else if (m < 4352) { int mm=m-3584; int t=mm>>6,b=mm&63; row = wr[b*12+t]; emb = we; }
  else               { int mm=m-4352; int t=mm>>6,b=mm&63; row = rr[b*4 +t]; emb = re; }
  XALL[(size_t)m*300 + k] = emb[(size_t)row*300 + k];
}

// ================= generic tiled fp32 GEMM: C[M][N] = A[M][K] @ B[K][N] (+bias[N]) =========
template<bool BIAS>
__global__ __launch_bounds__(256) void k_gemm(
    const float* __restrict__ A, const float* __restrict__ Bm,
    const float* __restrict__ bias, float* __restrict__ C,
    int M, int N, int K) {
  __shared__ float As[16][68];
  __shared__ float Bs[16][68];
  int tid = threadIdx.x;
  int tx = tid & 15, ty = tid >> 4;
  int m0 = blockIdx.x << 6, n0 = blockIdx.y << 6;
  int mm = tid >> 2, kq = (tid & 3) << 2;
  int nn = tid & 63, kb = tid >> 6;
  float acc[4][4] = {};
  for (int k0 = 0; k0 < K; k0 += 16) {
    const float* ap = A + (size_t)(m0 + mm) * K + k0 + kq;
    float4 av;
    if (k0 + kq + 3 < K) av = *(const float4*)ap;
    else {
      av.x = (k0+kq+0 < K) ? ap[0] : 0.f;
      av.y = (k0+kq+1 < K) ? ap[1] : 0.f;
      av.z = (k0+kq+2 < K) ? ap[2] : 0.f;
      av.w = (k0+kq+3 < K) ? ap[3] : 0.f;
    }
    As[kq+0][mm]=av.x; As[kq+1][mm]=av.y; As[kq+2][mm]=av.z; As[kq+3][mm]=av.w;
#pragma unroll
    for (int i = 0; i < 4; i++) {
      int kk = kb + (i << 2);
      Bs[kk][nn] = (k0 + kk < K) ? Bm[(size_t)(k0+kk)*N + n0 + nn] : 0.f;
    }
    __syncthreads();
#pragma unroll
    for (int kk = 0; kk < 16; kk++) {
      float4 a4 = *(const float4*)&As[kk][ty << 2];
      float4 b4 = *(const float4*)&Bs[kk][tx << 2];
      acc[0][0]+=a4.x*b4.x; acc[0][1]+=a4.x*b4.y; acc[0][2]+=a4.x*b4.z; acc[0][3]+=a4.x*b4.w;
      acc[1][0]+=a4.y*b4.x; acc[1][1]+=a4.y*b4.y; acc[1][2]+=a4.y*b4.z; acc[1][3]+=a4.y*b4.w;
      acc[2][0]+=a4.z*b4.x; acc[2][1]+=a4.z*b4.y; acc[2][2]+=a4.z*b4.z; acc[2][3]+=a4.z*b4.w;
      acc[3][0]+=a4.w*b4.x; acc[3][1]+=a4.w*b4.y; acc[3][2]+=a4.w*b4.z; acc[3][3]+=a4.w*b4.w;
    }
    __syncthreads();
  }
#pragma unroll
  for (int i = 0; i < 4; i++) {
    int row = m0 + (ty << 2) + i;
    float4 o4 = make_float4(acc[i][0], acc[i][1], acc[i][2], acc[i][3]);
    if (BIAS) {
      float4 bv = *(const float4*)(bias + n0 + (tx << 2));
      o4.x += bv.x; o4.y += bv.y; o4.z += bv.z; o4.w += bv.w;
    }
    *(float4*)(C + (size_t)row * N + n0 + (tx << 2)) = o4;
  }
}

// ================= one recurrent step, all active (seq,dir) slots =================
// thread = hidden unit u; block covers BB batches; slot = blockIdx.y
template<int BB>
__global__ __launch_bounds__(256) void k_step(
    const float* __restrict__ WQ, const float* __restrict__ XP,
    float* __restrict__ hsQ, float* __restrict__ hsWp, float* __restrict__ hsRp,
    float* __restrict__ hsWr, float* __restrict__ hsRr, float* __restrict__ CS,
    int step) {
  int slot = blockIdx.y;
  int dir = slot & 1, si = slot >> 1;
  int t, T, seg; float* hs; float* cs;
  const float* ih = nullptr; const float* ic = nullptr;
  if (si == 0) { t = step; T = 40; seg = 0; hs = hsQ; cs = CS + (size_t)(0 + dir) * BH; }
  else if (step < 12) {
    t = step; T = 12;
    if (si == 1) { seg = 2560; hs = hsWp; cs = CS + (size_t)(2 + dir) * BH; }
    else         { seg = 3584; hs = hsWr; cs = CS + (size_t)(6 + dir) * BH; }
  } else {
    t = step - 12; T = 4;
    if (si == 1) { seg = 3328; hs = hsRp; cs = CS + (size_t)(4 + dir) * BH;
                   ih = hsWp + (size_t)(dir*12 + 11) * BH; ic = CS + (size_t)(2 + dir) * BH; }
    else         { seg = 4352; hs = hsRr; cs = CS + (size_t)(8 + dir) * BH;
                   ih = hsWr + (size_t)(dir*12 + 11) * BH; ic = CS + (size_t)(6 + dir) * BH; }
  }
  hs += (size_t)dir * T * BH;
  int b0 = blockIdx.x * BB;
  int u = threadIdx.x;

  __shared__ float hl[BB][260];
  for (int i = threadIdx.x; i < BB * 256; i += 256) {
    int bb = i >> 8, uu = i & 255;
    float v;
    if (t == 0) v = ih ? ih[(b0 + bb) * 256 + uu] : 0.f;
    else        v = hs[(size_t)(t-1) * BH + (b0 + bb) * 256 + uu];
    hl[bb][uu] = v;
  }
  __syncthreads();

  float acc[4][BB];
#pragma unroll
  for (int g = 0; g < 4; g++)
#pragma unroll
    for (int b = 0; b < BB; b++) acc[g][b] = 0.f;

  const float* wb = WQ + (size_t)dir * 262144 + u * 4;
#pragma unroll 2
  for (int k4 = 0; k4 < 64; k4++) {
    float4 w0 = *(const float4*)(wb + k4*4096);
    float4 w1 = *(const float4*)(wb + k4*4096 + 1024);
    float4 w2 = *(const float4*)(wb + k4*4096 + 2048);
    float4 w3 = *(const float4*)(wb + k4*4096 + 3072);
#pragma unroll
    for (int b = 0; b < BB; b++) {
      float4 h4 = *(const float4*)&hl[b][k4*4];
      acc[0][b] += w0.x*h4.x + w0.y*h4.y + w0.z*h4.z + w0.w*h4.w;
      acc[1][b] += w1.x*h4.x + w1.y*h4.y + w1.z*h4.z + w1.w*h4.w;
      acc[2][b] += w2.x*h4.x + w2.y*h4.y + w2.z*h4.z + w2.w*h4.w;
      acc[3][b] += w3.x*h4.x + w3.y*h4.y + w3.z*h4.z + w3.w*h4.w;
    }
  }

  int t_in = dir ? (T - 1 - t) : t;
#pragma unroll
  for (int b = 0; b < BB; b++) {
    const float* xr = XP + (size_t)(seg + t_in*64 + b0 + b) * 2048 + dir*1024 + u;
    float zi = acc[0][b] + xr[0];
    float zf = acc[1][b] + xr[256];
    float zg = acc[2][b] + xr[512];
    float zo = acc[3][b] + xr[768];
    float cprev;
    if (t == 0) cprev = ic ? ic[(b0 + b) * 256 + u] : 0.f;
    else        cprev = cs[(b0 + b) * 256 + u];
    float gi = 1.f / (1.f + expf(-zi));
    float gf = 1.f / (1.f + expf(-zf));
    float go = 1.f / (1.f + expf(-zo));
    float gg = tanhf(zg);
    float cn = gf * cprev + gi * gg;
    float hn = go * tanhf(cn);
    cs[(b0 + b) * 256 + u] = cn;
    hs[(size_t)t * BH + (b0 + b) * 256 + u] = hn;
  }
}

// ================= question_out as [b][s][h] =================
__global__ __launch_bounds__(256) void k_qo1(const float* __restrict__ hsQ, float* __restrict__ QT) {
  int idx = blockIdx.x * 256 + threadIdx.x;
  if (idx >= 64*40*512) return;
  int h = idx & 511; int t2 = idx >> 9; int s = t2 % 40; int b = t2 / 40;
  float v;
  if (h < 256) v = hsQ[(size_t)s * BH + b*256 + h];
  else         v = hsQ[(size_t)40 * BH + (size_t)(39 - s) * BH + b*256 + (h - 256)];
  QT[idx] = v;
}

// ================= relation tensors [b][r][h], both calls =================
__global__ __launch_bounds__(256) void k_rel(
    const float* __restrict__ hsWp, const float* __restrict__ hsRp,
    const float* __restrict__ hsWr, const float* __restrict__ hsRr,
    float* __restrict__ RELP, float* __restrict__ RELC) {
  int idx0 = blockIdx.x * 256 + threadIdx.x;
  if (idx0 >= 2*64*16*512) return;
  int call = idx0 >= 64*16*512;
  int idx = idx0 - call * 64*16*512;
  int h = idx & 511; int t2 = idx >> 9; int r = t2 & 15; int b = t2 >> 4;
  const float* hsW = call ? hsWr : hsWp;
  const float* hsR = call ? hsRr : hsRp;
  float v;
  if (r < 4) {
    if (h < 256) v = hsR[(size_t)r * BH + b*256 + h];
    else         v = hsR[(size_t)4 * BH + (size_t)(3 - r) * BH + b*256 + (h - 256)];
  } else {
    int t = r - 4;
    if (h < 256) v = hsW[(size_t)t * BH + b*256 + h];
    else         v = hsW[(size_t)12 * BH + (size_t)(11 - t) * BH + b*256 + (h - 256)];
  }
  (call ? RELC : RELP)[idx] = v;
}

// ================= energy[b][r][s] = relW[b,r,:] . QT[b,s,:] =================
__global__ __launch_bounds__(256) void k_energy(
    const float* __restrict__ relW, const float* __restrict__ QT, float* __restrict__ EN) {
  int idx = blockIdx.x * 256 + threadIdx.x;
  if (idx >= 64*16*40) return;
  int s = idx % 40; int t = idx / 40; int r = t & 15; int b = t >> 4;
  const float* rw = relW + (size_t)(b*16 + r) * 512;
  const float* qv = QT   + (size_t)(b*40 + s) * 512;
  float acc = 0.f;
#pragma unroll 4
  for (int k = 0; k < 512; k += 4) {
    float4 a = *(const float4*)(rw + k);
    float4 c = *(const float4*)(qv + k);
    acc += a.x*c.x + a.y*c.y + a.z*c.z + a.w*c.w;
  }
  EN[idx] = acc;
}

// ================= softmax over 640 per b (in place, scale=0.25) =================
__global__ __launch_bounds__(256) void k_softmax(float* __restrict__ EN) {
  int b = blockIdx.x; int tid = threadIdx.x;
  float* e = EN + b * 640;
  float v0 = e[tid] * 0.25f, v1 = e[tid + 256] * 0.25f;
  float v2 = (tid < 128) ? e[tid + 512] * 0.25f : NEG_INF;
  __shared__ float sh[256];
  sh[tid] = fmaxf(v0, fmaxf(v1, v2));
  __syncthreads();
  for (int st = 128; st > 0; st >>= 1) { if (tid < st) sh[tid] = fmaxf(sh[tid], sh[tid+st]); __syncthreads(); }
  float m = sh[0];
  __syncthreads();
  float e0 = expf(v0 - m), e1 = expf(v1 - m);
  float e2 = (tid < 128) ? expf(v2 - m) : 0.f;
  sh[tid] = e0 + e1 + e2;
  __syncthreads();
  for (int st = 128; st > 0; st >>= 1) { if (tid < st) sh[tid] += sh[tid+st]; __syncthreads(); }
  float inv = 1.f / sh[0];
  e[tid] = e0 * inv; e[tid + 256] = e1 * inv;
  if (tid < 128) e[tid + 512] = e2 * inv;
}

// ================= atten[b][s][h] = sum_r alpha[b,r,s]*rel[b,r,h] =================
__global__ __launch_bounds__(256) void k_atten(
    const float* __restrict__ AL, const float* __restrict__ REL, float* __restrict__ ATT) {
  int idx = blockIdx.x * 256 + threadIdx.x;
  if (idx >= 64*40*512) return;
  int h = idx & 511; int t2 = idx >> 9; int s = t2 % 40; int b = t2 / 40;
  const float* al = AL + b * 640 + s;
  const float* rl = REL + (size_t)b * 16 * 512 + h;
  float acc = 0.f;
#pragma unroll
  for (int r = 0; r < 16; r++) acc += al[r*40] * rl[r*512];
  ATT[idx] = acc;
}

__global__ __launch_bounds__(256) void k_sub(
    const float* __restrict__ QT, const float* __restrict__ ATT, float* __restrict__ D) {
  int idx = blockIdx.x * 256 + threadIdx.x;
  if (idx < 64*40*512) D[idx] = QT[idx] - ATT[idx];
}

// ================= pack M as [b][c][l] =================
__global__ __launch_bounds__(256) void k_mt(
    const float* __restrict__ QO2, const float* __restrict__ ATT, float* __restrict__ MT) {
  int idx = blockIdx.x * 256 + threadIdx.x;
  if (idx >= 64*1024*40) return;
  int l = idx % 40; int t = idx / 40; int c = t & 1023; int b = t >> 10;
  float v = (c < 512) ? QO2[(size_t)(b*40 + l)*512 + c]
                      : ATT[(size_t)(b*40 + l)*512 + (c - 512)];
  MT[idx] = v;
}

// ================= fused conv1/3/5 + relu + maxpool, per (b,o) =================
__global__ __launch_bounds__(128) void k_conv(
    const float* __restrict__ MT,
    const float* __restrict__ w1, const float* __restrict__ b1,
    const float* __restrict__ w2, const float* __restrict__ b2,
    const float* __restrict__ w3, const float* __restrict__ b3,
    float* __restrict__ HM) {
  int b = blockIdx.x, o = blockIdx.y;
  int tid = threadIdx.x;
  const float* Mb = MT + (size_t)b * 1024 * 40;
  float acc = NEG_INF;
  if (tid < 40) {                  // K=1
    int l = tid; float s = b1[o];
    const float* w = w1 + (size_t)o * 1024;
    for (int c = 0; c < 1024; c++) s += Mb[c*40 + l] * w[c];
    acc = s;
  } else if (tid < 78) {           // K=3
    int l = tid - 40; float s = b2[o];
    const float* w = w2 + (size_t)o * 3072;
    for (int c = 0; c < 1024; c++) {
      const float* m = Mb + c*40 + l;
      const float* ww = w + c*3;
      s += m[0]*ww[0] + m[1]*ww[1] + m[2]*ww[2];
    }
    acc = s;
  } else if (tid < 114) {          // K=5
    int l = tid - 78; float s = b3[o];
    const float* w = w3 + (size_t)o * 5120;
    for (int c = 0; c < 1024; c++) {
      const float* m = Mb + c*40 + l;
      const float* ww = w + c*5;
      s += m[0]*ww[0] + m[1]*ww[1] + m[2]*ww[2] + m[3]*ww[3] + m[4]*ww[4];
    }
    acc = s;
  }
  __shared__ float sh[128];
  sh[tid] = acc;
  __syncthreads();
  for (int st = 64; st > 0; st >>= 1) { if (tid < st) sh[tid] = fmaxf(sh[tid], sh[tid+st]); __syncthreads(); }
  if (tid == 0) HM[b*150 + o] = fmaxf(sh[0], 0.f);
}

__global__ __launch_bounds__(64) void k_score(
    const float* __restrict__ HM, const float* __restrict__ lw, float* __restrict__ out) {
  int b = threadIdx.x;
  float acc = 0.f;
  for (int o = 0; o < 150; o++) acc += HM[b*150 + o] * lw[o];
  out[b] = acc;
}

// ================= host =================
extern "C" void kernel_launch(void* const* d_in, const int* in_sizes, int n_in,
                              void* d_out, int out_size, void* d_ws, size_t ws_size,
                              hipStream_t stream) {
  const int*   q    = (const int*)d_in[0];
  const int*   wrel = (const int*)d_in[1];
  const int*   rrel = (const int*)d_in[2];
  const int*   wprv = (const int*)d_in[3];
  const int*   rprv = (const int*)d_in[4];
  const float* we   = (const float*)d_in[5];
  const float* re   = (const float*)d_in[6];
  const float* Wih_f= (const float*)d_in[7];
  const float* Whh_f= (const float*)d_in[8];
  const float* b_f  = (const float*)d_in[9];
  const float* Wih_b= (const float*)d_in[10];
  const float* Whh_b= (const float*)d_in[11];
  const float* b_b  = (const float*)d_in[12];
  const float* W    = (const float*)d_in[13];
  const float* c1w  = (const float*)d_in[14];
  const float* c1b  = (const float*)d_in[15];
  const float* c2w  = (const float*)d_in[16];
  const float* c2b  = (const float*)d_in[17];
  const float* c3w  = (const float*)d_in[18];
  const float* c3b  = (const float*)d_in[19];
  const float* lw   = (const float*)d_in[20];
  const float* l2w  = (const float*)d_in[21];
  const float* l2b  = (const float*)d_in[22];
  float* out = (float*)d_out;
  float* ws  = (float*)d_ws;

  float* WIHT = ws + OFF_WIHT;
  float* WQk  = ws + OFF_WQ;
  float* L2T  = ws + OFF_L2T;
  float* B2   = ws + OFF_B2;
  float* XALL = ws + OFF_XALL;
  float* XP   = ws + OFF_XP;
  float* HSQ  = ws + OFF_HSQ;
  float* HSWP = ws + OFF_HSWP;
  float* HSRP = ws + OFF_HSRP;
  float* HSWR = ws + OFF_HSWR;
  float* HSRR = ws + OFF_HSRR;
  float* CS   = ws + OFF_CS;
  float* QO1  = ws + OFF_QO1;
  float* RELP = ws + OFF_RELP;
  float* RELC = ws + OFF_RELC;
  float* RELW = ws + OFF_RELW;
  float* EN   = ws + OFF_EN;
  float* ATT  = ws + OFF_ATT;
  float* HM   = ws + OFF_HM;
  // aliases into dead XP region
  float* Dbuf = XP;
  float* QO2  = XP + 1310720;
  float* MT   = XP + 2621440;

  k_prep<<<5480, 256, 0, stream>>>(Wih_f, Wih_b, Whh_f, Whh_b, b_f, b_b, l2w,
                                   WIHT, WQk, L2T, B2);
  k_gather<<<NTOK, 320, 0, stream>>>(q, wrel, rrel, wprv, rprv, we, re, XALL);
  { dim3 g(72, 32); k_gemm<true><<<g, 256, 0, stream>>>(XALL, WIHT, B2, XP, NTOK, 2048, 300); }

  for (int s = 0; s < 40; s++) {
    if (s < 16) { dim3 g(16, 6); k_step<4><<<g, 256, 0, stream>>>(WQk, XP, HSQ, HSWP, HSRP, HSWR, HSRR, CS, s); }
    else        { dim3 g(32, 2); k_step<2><<<g, 256, 0, stream>>>(WQk, XP, HSQ, HSWP, HSRP, HSWR, HSRR, CS, s); }
  }

  k_qo1<<<5120, 256, 0, stream>>>(HSQ, QO1);
  k_rel<<<4096, 256, 0, stream>>>(HSWP, HSRP, HSWR, HSRR, RELP, RELC);

  // ---- attention (previous hop) ----
  { dim3 g(16, 8); k_gemm<false><<<g, 256, 0, stream>>>(RELP, W, nullptr, RELW, 1024, 512, 512); }
  k_energy<<<160, 256, 0, stream>>>(RELW, QO1, EN);
  k_softmax<<<64, 256, 0, stream>>>(EN);
  k_atten<<<5120, 256, 0, stream>>>(EN, RELP, ATT);
  k_sub<<<5120, 256, 0, stream>>>(QO1, ATT, Dbuf);
  { dim3 g(40, 8); k_gemm<true><<<g, 256, 0, stream>>>(Dbuf, L2T, l2b, QO2, 2560, 512, 512); }

  // ---- attention (current relation) ----
  { dim3 g(16, 8); k_gemm<false><<<g, 256, 0, stream>>>(RELC, W, nullptr, RELW, 1024, 512, 512); }
  k_energy<<<160, 256, 0, stream>>>(RELW, QO2, EN);
  k_softmax<<<64, 256, 0, stream>>>(EN);
  k_atten<<<5120, 256, 0, stream>>>(EN, RELC, ATT);

  // ---- convs + score ----
  k_mt<<<10240, 256, 0, stream>>>(QO2, ATT, MT);
  { dim3 g(64, 150); k_conv<<<g, 128, 0, stream>>>(MT, c1w, c1b, c2w, c2b, c3w, c3b, HM); }
  k_score<<<1, 64, 0, stream>>>(HM, lw, out);
}